// Round 4
// baseline (141.468 us; speedup 1.0000x reference)
//
#include <hip/hip_runtime.h>

// LatticeFilter: step-up (Levinson-Durbin) recursion, rc -> LPC coeffs.
//   rc: (B=16, p=128, Tf=8192) fp32, k_i = 0.98*rc[b,i,t]
//   out: (B, Tf, p+1=129) fp32, a[...,0]=1
//
// R4: R3's template recursion STILL ran from scratch (VGPR=100, dur
// unchanged). Root cause: SROA runs once, early; the epilogue staging loop
// `lds[...+j] = a[j]` had a dynamic GEP into the alloca at SROA time, which
// disqualifies the WHOLE array from promotion — the 8128-FMA recursion then
// runs against scratch memory. Fix: the staging loop is template recursion
// too, so after inlining every access to a[] is a constant-index GEP and
// SROA promotes all 129 elements to registers.

#define NB   16
#define ORD  128
#define TF   8192

// ---- step-up recursion, fully static ----
template<int M, int J>
struct PairUpd {
    static __device__ __forceinline__ void run(float (&a)[ORD + 1], float k) {
        const float lo = a[J];
        const float hi = a[M - J];
        a[J]     = fmaf(k, hi, lo);
        a[M - J] = fmaf(k, lo, hi);
        if constexpr (2 * (J + 1) < M) PairUpd<M, J + 1>::run(a, k);
    }
};

template<int M>
struct Step {
    static __device__ __forceinline__ void run(float (&a)[ORD + 1],
                                               const float* __restrict__ rcp) {
        const float k = 0.98f * rcp[(size_t)(M - 1) * TF];
        if constexpr (2 < M) PairUpd<M, 1>::run(a, k);
        if constexpr ((M & 1) == 0) {          // middle element self-update
            const float mid = a[M / 2];
            a[M / 2] = fmaf(k, mid, mid);
        }
        a[M] = k;                              // a[0] == 1 contributes k
        if constexpr (M < ORD) Step<M + 1>::run(a, rcp);
    }
};

// ---- LDS staging with static indices only ----
template<int J>
struct Stage {
    static __device__ __forceinline__ void run(float* __restrict__ dst,
                                               const float (&a)[ORD + 1]) {
        dst[J] = a[J];                         // constant offset -> SROA-safe
        if constexpr (J < ORD) Stage<J + 1>::run(dst, a);
    }
};

__global__ __launch_bounds__(256, 2)
void lpc_stepup_kernel(const float* __restrict__ rc, float* __restrict__ out) {
    const int tid = threadIdx.x;
    const int gid = blockIdx.x * 256 + tid;   // flattened (B*Tf) column
    const int b = gid >> 13;                  // gid / TF
    const int t = gid & (TF - 1);             // gid % TF
    const float* rcp = rc + ((size_t)b * ORD) * TF + t;

    float a[ORD + 1];
    a[0] = 1.0f;
    Step<1>::run(a, rcp);                     // straight-line, register-resident

    // ---- epilogue: transpose 256 rows x 129 cols through LDS, 4 rounds ----
    // stage: bank = (row + J) % 32 across the wave -> exact 2-way alias = free
    // store: 2064 contiguous float4 per round -> every 128B line written whole
    __shared__ __align__(16) float lds[64 * (ORD + 1)];   // 33,024 B
    const int my_round = tid >> 6;            // wave index — uniform branch
    const int row      = tid & 63;
    float* out_block = out + (size_t)blockIdx.x * 256 * (ORD + 1);

    for (int r = 0; r < 4; ++r) {
        __syncthreads();
        if (my_round == r)
            Stage<0>::run(&lds[row * (ORD + 1)], a);
        __syncthreads();
        const float4* lds4 = (const float4*)lds;
        float4* out4 = (float4*)(out_block + (size_t)r * 64 * (ORD + 1));
        for (int e = tid; e < (64 * (ORD + 1)) / 4; e += 256)
            out4[e] = lds4[e];                // perfectly coalesced
    }
}

extern "C" void kernel_launch(void* const* d_in, const int* in_sizes, int n_in,
                              void* d_out, int out_size, void* d_ws, size_t ws_size,
                              hipStream_t stream) {
    // d_in[0] = excitation (dead in reference), d_in[1] = rc
    const float* rc = (const float*)d_in[1];
    float* out = (float*)d_out;
    dim3 grid((NB * TF) / 256);
    dim3 block(256);
    hipLaunchKernelGGL(lpc_stepup_kernel, grid, block, 0, stream, rc, out);
}

// Round 5
// 134.649 us; speedup vs baseline: 1.0506x; 1.0506x over previous
//
#include <hip/hip_runtime.h>

// LatticeFilter: step-up (Levinson-Durbin) recursion, rc -> LPC coeffs.
//   rc: (B=16, p=128, Tf=8192) fp32, k_i = 0.98*rc[b,i,t]
//   out: (B, Tf, p+1=129) fp32, a[...,0]=1
//
// R5 theory: a[] was ALWAYS register-resident (scratch residency is
// arithmetically impossible at 56us: would need 152 TB/s through caches).
// The 2x VALU overhead is v_accvgpr shuttling: the pre-RA scheduler targets
// max achievable occupancy (launch_bounds' 2nd arg is only a MINIMUM),
// holding arch VGPRs at ~100 and pushing the rest of the state into AGPRs.
// The grid only supplies 2 waves/SIMD, so that occupancy is never used.
// Fixes:
//  (a) amdgpu_waves_per_eu(2,2): pin scheduler target = 2 -> 256-reg budget,
//      whole state in arch VGPRs, no shuttle instructions.
//  (b) per-step compiler memory fence: stop mass-hoisting of the 128 k-loads
//      (128 in-flight loads + 129 coeffs would blow the budget again);
//      PD=16 ring keeps exactly 16 loads in flight, ~16 steps of slack each.

#define NB   16
#define ORD  128
#define TF   8192
#define PD   16   // k prefetch distance (power of 2)

// ---- pair update j <-> m-j, both reading pre-step values (tmp-swap) ----
template<int M, int J>
struct PairUpd {
    static __device__ __forceinline__ void run(float (&a)[ORD + 1], float k) {
        const float lo = a[J];
        const float hi = a[M - J];
        a[J]     = fmaf(k, hi, lo);
        a[M - J] = fmaf(k, lo, hi);
        if constexpr (2 * (J + 1) < M) PairUpd<M, J + 1>::run(a, k);
    }
};

template<int M>
struct Step {
    static __device__ __forceinline__ void run(float (&a)[ORD + 1],
                                               float (&kq)[PD],
                                               const float* __restrict__ rcp) {
        constexpr int slot = (M - 1) & (PD - 1);
        const float k = 0.98f * kq[slot];
        if constexpr (M - 1 + PD < ORD)        // refill slot for step M+PD
            kq[slot] = rcp[(size_t)(M - 1 + PD) * TF];
        asm volatile("" ::: "memory");          // throttle: <= PD loads in flight
        if constexpr (M > 2) PairUpd<M, 1>::run(a, k);
        if constexpr ((M & 1) == 0) {           // middle element self-update
            const float mid = a[M / 2];
            a[M / 2] = fmaf(k, mid, mid);
        }
        a[M] = k;                               // a[0] == 1 contributes k
        if constexpr (M < ORD) Step<M + 1>::run(a, kq, rcp);
    }
};

// ---- LDS staging, static indices (compiler merges into ds_write_b128) ----
template<int J>
struct Stage {
    static __device__ __forceinline__ void run(float* __restrict__ dst,
                                               const float (&a)[ORD + 1]) {
        dst[J] = a[J];
        if constexpr (J < ORD) Stage<J + 1>::run(dst, a);
    }
};

__global__ __launch_bounds__(256)
__attribute__((amdgpu_waves_per_eu(2, 2)))
void lpc_stepup_kernel(const float* __restrict__ rc, float* __restrict__ out) {
    const int tid = threadIdx.x;
    const int gid = blockIdx.x * 256 + tid;   // flattened (B*Tf) column
    const int b = gid >> 13;                  // gid / TF
    const int t = gid & (TF - 1);             // gid % TF
    const float* rcp = rc + ((size_t)b * ORD) * TF + t;

    float kq[PD];
#pragma unroll
    for (int i = 0; i < PD; ++i) kq[i] = rcp[(size_t)i * TF];

    float a[ORD + 1];
    a[0] = 1.0f;
    Step<1>::run(a, kq, rcp);                 // straight-line, register-resident

    // ---- epilogue: transpose 256 rows x 129 cols through LDS, 4 rounds ----
    // stage: bank stride 1 (129 mod 32 = 1) -> free 2-way wave64 aliasing
    // store: 2064 contiguous float4 per round -> every 128B line written whole
    __shared__ __align__(16) float lds[64 * (ORD + 1)];   // 33,024 B
    const int my_round = tid >> 6;            // wave index — uniform branch
    const int row      = tid & 63;
    float* out_block = out + (size_t)blockIdx.x * 256 * (ORD + 1);

    for (int r = 0; r < 4; ++r) {
        __syncthreads();
        if (my_round == r)
            Stage<0>::run(&lds[row * (ORD + 1)], a);
        __syncthreads();
        const float4* lds4 = (const float4*)lds;
        float4* out4 = (float4*)(out_block + (size_t)r * 64 * (ORD + 1));
        for (int e = tid; e < (64 * (ORD + 1)) / 4; e += 256)
            out4[e] = lds4[e];                // perfectly coalesced
    }
}

extern "C" void kernel_launch(void* const* d_in, const int* in_sizes, int n_in,
                              void* d_out, int out_size, void* d_ws, size_t ws_size,
                              hipStream_t stream) {
    // d_in[0] = excitation (dead in reference), d_in[1] = rc
    const float* rc = (const float*)d_in[1];
    float* out = (float*)d_out;
    dim3 grid((NB * TF) / 256);
    dim3 block(256);
    hipLaunchKernelGGL(lpc_stepup_kernel, grid, block, 0, stream, rc, out);
}